// Round 1
// baseline (44.536 us; speedup 1.0000x reference)
//
#include <hip/hip_runtime.h>

#define POPN  4096
#define LENN  2048
#define GRIDN 512
#define NWORDS (GRIDN * GRIDN / 32)   // 8192 u32 per bitmap (32 KB)
#define TPB   512

__global__ __launch_bounds__(TPB) void fitness_kernel(
    const float* __restrict__ pop,
    const float* __restrict__ tp,
    float* __restrict__ out)
{
    __shared__ unsigned seen[NWORDS];  // bit set -> code visited >= 1 time
    __shared__ unsigned dupb[NWORDS];  // bit set -> code visited >= 2 times

    const int tid  = threadIdx.x;
    const int path = blockIdx.x;

    // Zero both bitmaps with 16B LDS stores (8 ds_write_b128 / thread).
    {
        uint4 z = make_uint4(0u, 0u, 0u, 0u);
        uint4* s4 = (uint4*)seen;
        uint4* d4 = (uint4*)dupb;
        #pragma unroll
        for (int i = tid; i < NWORDS / 4; i += TPB) { s4[i] = z; d4[i] = z; }
    }
    __syncthreads();

    const float*  p  = pop + (size_t)path * (LENN * 2);
    const float4* p4 = (const float4*)p;

    // Thread t owns points [4t, 4t+4); load 8 floats = 4 points, plus the
    // first point of the next chunk for the continuity step at the seam.
    float4 a = p4[tid * 2];
    float4 b = p4[tid * 2 + 1];
    float xs[5], ys[5];
    xs[0] = a.x; ys[0] = a.y;
    xs[1] = a.z; ys[1] = a.w;
    xs[2] = b.x; ys[2] = b.y;
    xs[3] = b.z; ys[3] = b.w;

    const int base = tid * 4;
    int nsteps = 3;                    // last thread: steps 2044..2046 only
    if (base + 4 < LENN) {
        float2 c = ((const float2*)p)[base + 4];   // same cache line as next thread's load
        xs[4] = c.x; ys[4] = c.y;
        nsteps = 4;
    } else {
        xs[4] = xs[3]; ys[4] = ys[3];  // dummy (step masked out below)
    }

    float reward = 0.0f;
    int   dupc   = 0;
    #pragma unroll
    for (int j = 0; j < 4; ++j) {
        int x = (int)xs[j];
        int y = (int)ys[j];
        int code = x * GRIDN + y;                  // [0, 262144)
        reward += tp[code];                        // random gather, L2-resident
        unsigned w   = (unsigned)code >> 5;
        unsigned bit = 1u << (code & 31);
        unsigned old = atomicOr(&seen[w], bit);
        if (old & bit) {                           // second-or-later visit
            unsigned old2 = atomicOr(&dupb[w], bit);
            if (!(old2 & bit)) dupc++;             // exactly one thread counts it
        }
    }

    int cont = 0;
    #pragma unroll
    for (int j = 0; j < 4; ++j) {
        if (j < nsteps) {
            float d = fabsf(xs[j + 1] - xs[j]) + fabsf(ys[j + 1] - ys[j]);
            if (d > 1.0f) cont++;
        }
    }

    float fit = reward - 0.5f * (float)cont - 0.2f * (float)dupc;

    // Wave (64-lane) shuffle reduce, then cross-wave via reused LDS.
    #pragma unroll
    for (int off = 32; off > 0; off >>= 1)
        fit += __shfl_down(fit, off, 64);

    __syncthreads();                   // all atomics done; safe to reuse seen[]
    float* scratch = (float*)seen;
    if ((tid & 63) == 0) scratch[tid >> 6] = fit;
    __syncthreads();
    if (tid == 0) {
        float s = 0.0f;
        #pragma unroll
        for (int w2 = 0; w2 < TPB / 64; ++w2) s += scratch[w2];
        out[path] = s;
    }
}

extern "C" void kernel_launch(void* const* d_in, const int* in_sizes, int n_in,
                              void* d_out, int out_size, void* d_ws, size_t ws_size,
                              hipStream_t stream) {
    const float* pop = (const float*)d_in[0];   // [POP, LEN, 2] f32
    const float* tp  = (const float*)d_in[1];   // [GRID, GRID] f32
    float* out = (float*)d_out;                 // [POP] f32
    (void)in_sizes; (void)n_in; (void)out_size; (void)d_ws; (void)ws_size;

    fitness_kernel<<<POPN, TPB, 0, stream>>>(pop, tp, out);
}